// Round 1
// baseline (404.894 us; speedup 1.0000x reference)
//
#include <hip/hip_runtime.h>
#include <hip/hip_bf16.h>
#include <stdint.h>

#define B_DIM 8192
#define K_DIM 2048
#define N_DIM 2048
#define NSEG 4

#define BM 128
#define BN 32
#define BK 32

typedef short bf16x8 __attribute__((ext_vector_type(8)));   // 8 bf16 (4 VGPRs)
typedef float f32x4 __attribute__((ext_vector_type(4)));
typedef unsigned short ushort8v __attribute__((ext_vector_type(8)));

typedef const __attribute__((address_space(1))) void* gas_ptr;
typedef __attribute__((address_space(3))) void* lds_ptr;

__device__ __forceinline__ unsigned short f2bf(float f) {
  uint32_t u = __float_as_uint(f);
  u += 0x7FFFu + ((u >> 16) & 1u);   // round-to-nearest-even
  return (unsigned short)(u >> 16);
}

// ---------------- f32 -> bf16 conversion, 8 elems/thread ----------------
__global__ __launch_bounds__(256)
void convert_kernel(const float* __restrict__ in, unsigned short* __restrict__ out, int n8) {
  int i = blockIdx.x * blockDim.x + threadIdx.x;
  const int stride = gridDim.x * blockDim.x;
  for (; i < n8; i += stride) {
    const float4* p = (const float4*)(in + (size_t)i * 8);
    float4 v0 = p[0];
    float4 v1 = p[1];
    ushort8v r;
    r[0] = f2bf(v0.x); r[1] = f2bf(v0.y); r[2] = f2bf(v0.z); r[3] = f2bf(v0.w);
    r[4] = f2bf(v1.x); r[5] = f2bf(v1.y); r[6] = f2bf(v1.z); r[7] = f2bf(v1.w);
    *(ushort8v*)(out + (size_t)i * 8) = r;
  }
}

// ---------------- gates: sigmoid(x @ W_gate.T + b_gate), fp32 ----------------
__global__ __launch_bounds__(256)
void gates_kernel(const float* __restrict__ x, const float* __restrict__ Wg,
                  const float* __restrict__ bg, float* __restrict__ gates) {
  const int b = blockIdx.x;
  const int tid = threadIdx.x;
  const float4* xr = (const float4*)(x + (size_t)b * K_DIM);
  float a0 = 0.f, a1 = 0.f, a2 = 0.f, a3 = 0.f;
  for (int i = tid; i < K_DIM / 4; i += 256) {
    float4 xv = xr[i];
    float4 w0 = ((const float4*)(Wg + 0 * K_DIM))[i];
    float4 w1 = ((const float4*)(Wg + 1 * K_DIM))[i];
    float4 w2 = ((const float4*)(Wg + 2 * K_DIM))[i];
    float4 w3 = ((const float4*)(Wg + 3 * K_DIM))[i];
    a0 += xv.x * w0.x + xv.y * w0.y + xv.z * w0.z + xv.w * w0.w;
    a1 += xv.x * w1.x + xv.y * w1.y + xv.z * w1.z + xv.w * w1.w;
    a2 += xv.x * w2.x + xv.y * w2.y + xv.z * w2.z + xv.w * w2.w;
    a3 += xv.x * w3.x + xv.y * w3.y + xv.z * w3.z + xv.w * w3.w;
  }
#pragma unroll
  for (int off = 1; off < 64; off <<= 1) {
    a0 += __shfl_xor(a0, off);
    a1 += __shfl_xor(a1, off);
    a2 += __shfl_xor(a2, off);
    a3 += __shfl_xor(a3, off);
  }
  __shared__ float red[4][4];
  const int wv = tid >> 6;
  if ((tid & 63) == 0) { red[wv][0] = a0; red[wv][1] = a1; red[wv][2] = a2; red[wv][3] = a3; }
  __syncthreads();
  if (tid < 4) {
    float v = red[0][tid] + red[1][tid] + red[2][tid] + red[3][tid] + bg[tid];
    gates[(size_t)b * 4 + tid] = 1.f / (1.f + __expf(-v));
  }
}

// ---------------- fused 4-segment GEMM + epilogue ----------------
// Block tile: BM=128 (batch rows) x BN=32 (d_state cols), 4 segments.
// 256 threads = 4 waves, wave w owns rows [w*32, w*32+32), all 32 cols.
// Per wave: M_rep=2, N_rep=2, 4 segs -> acc[4][2][2] f32x4 = 64 VGPR.
__global__ __launch_bounds__(256, 4)
void seg_gemm_kernel(const unsigned short* __restrict__ Xb,
                     const unsigned short* __restrict__ Wb,
                     const float* __restrict__ b_seg,
                     const float* __restrict__ thr,
                     const float* __restrict__ gates,
                     float* __restrict__ out) {
  __shared__ __align__(16) unsigned short As[BM * BK];        // 8 KB
  __shared__ __align__(16) unsigned short Bs[NSEG * BN * BK]; // 8 KB

  const int tid = threadIdx.x;
  const int lane = tid & 63;
  const int wv = tid >> 6;               // 0..3 (m-direction)
  const int n0 = blockIdx.x * BN;        // d_state tile
  const int m0 = blockIdx.y * BM;        // batch tile

  f32x4 acc[NSEG][2][2];
#pragma unroll
  for (int s = 0; s < NSEG; ++s)
#pragma unroll
    for (int m = 0; m < 2; ++m)
#pragma unroll
      for (int n = 0; n < 2; ++n)
        acc[s][m][n] = (f32x4){0.f, 0.f, 0.f, 0.f};

  // staging decomposition (constant per thread)
  // A: 512 chunks of 16B; chunk c -> row=c>>2, colchunk=c&3
  // B: 512 chunks; chunk c -> s=c>>7, r=(c>>2)&31, colchunk=c&3
  const int acA = tid;            // + j*256
  const int colLo = lane & 15;
  const int kGrp = lane >> 4;

  for (int kt = 0; kt < K_DIM / BK; ++kt) {
    const int kb = kt * BK;
    __syncthreads();
#pragma unroll
    for (int j = 0; j < 2; ++j) {
      const int c = j * 256 + acA;
      const int row = c >> 2, cc = c & 3;
      const unsigned short* g = Xb + (size_t)(m0 + row) * K_DIM + kb + cc * 8;
      __builtin_amdgcn_global_load_lds((gas_ptr)g, (lds_ptr)(As + c * 8), 16, 0, 0);
    }
#pragma unroll
    for (int j = 0; j < 2; ++j) {
      const int c = j * 256 + acA;
      const int s = c >> 7, r = (c >> 2) & 31, cc = c & 3;
      const unsigned short* g =
          Wb + (size_t)s * (N_DIM * K_DIM) + (size_t)(n0 + r) * K_DIM + kb + cc * 8;
      __builtin_amdgcn_global_load_lds((gas_ptr)g, (lds_ptr)(Bs + c * 8), 16, 0, 0);
    }
    __syncthreads();

    const bf16x8 a0 = *(const bf16x8*)&As[(wv * 32 + colLo) * BK + kGrp * 8];
    const bf16x8 a1 = *(const bf16x8*)&As[(wv * 32 + 16 + colLo) * BK + kGrp * 8];
#pragma unroll
    for (int s = 0; s < NSEG; ++s) {
      const bf16x8 b0 = *(const bf16x8*)&Bs[(s * BN + colLo) * BK + kGrp * 8];
      const bf16x8 b1 = *(const bf16x8*)&Bs[(s * BN + 16 + colLo) * BK + kGrp * 8];
      acc[s][0][0] = __builtin_amdgcn_mfma_f32_16x16x32_bf16(a0, b0, acc[s][0][0], 0, 0, 0);
      acc[s][0][1] = __builtin_amdgcn_mfma_f32_16x16x32_bf16(a0, b1, acc[s][0][1], 0, 0, 0);
      acc[s][1][0] = __builtin_amdgcn_mfma_f32_16x16x32_bf16(a1, b0, acc[s][1][0], 0, 0, 0);
      acc[s][1][1] = __builtin_amdgcn_mfma_f32_16x16x32_bf16(a1, b1, acc[s][1][1], 0, 0, 0);
    }
  }

  // ---------------- epilogue ----------------
  // C/D layout: col = lane&15, row = (lane>>4)*4 + reg  [m89 verified]
  float bsv[2][NSEG], thv[2][NSEG];
#pragma unroll
  for (int n = 0; n < 2; ++n) {
    const int d = n0 + n * 16 + colLo;
#pragma unroll
    for (int s = 0; s < NSEG; ++s) {
      bsv[n][s] = b_seg[s * N_DIM + d];
      thv[n][s] = thr[s * N_DIM + d];
    }
  }
#pragma unroll
  for (int m = 0; m < 2; ++m) {
#pragma unroll
    for (int r = 0; r < 4; ++r) {
      const int b = m0 + wv * 32 + m * 16 + kGrp * 4 + r;
      const float4 g = *(const float4*)(gates + (size_t)b * 4);
      const float gv[NSEG] = {g.x, g.y, g.z, g.w};
#pragma unroll
      for (int n = 0; n < 2; ++n) {
        const int d = n0 + n * 16 + colLo;
        float sum = 0.f, prod = 1.f;
#pragma unroll
        for (int s = 0; s < NSEG; ++s) {
          const float seg = acc[s][m][n][r] + bsv[n][s];
          const float pl = 1.f / (1.f + __expf(-5.f * (seg - thv[n][s])));
          const float st = seg * pl * gv[s];
          sum += st;
          prod *= st;
        }
        const float gm = sqrtf(sqrtf(fabsf(prod)));   // |prod|^(1/4)
        out[(size_t)b * N_DIM + d] = sum + 0.1f * (prod < 0.f ? -gm : gm);
      }
    }
  }
}

extern "C" void kernel_launch(void* const* d_in, const int* in_sizes, int n_in,
                              void* d_out, int out_size, void* d_ws, size_t ws_size,
                              hipStream_t stream) {
  const float* x      = (const float*)d_in[0];
  const float* W_seg  = (const float*)d_in[1];
  const float* b_seg  = (const float*)d_in[2];
  const float* thr    = (const float*)d_in[3];
  const float* W_gate = (const float*)d_in[4];
  const float* b_gate = (const float*)d_in[5];
  float* out = (float*)d_out;

  // workspace layout: x_bf16 (32MB) | W_bf16 (32MB) | gates (128KB)
  unsigned short* xb = (unsigned short*)d_ws;
  unsigned short* wb = xb + (size_t)B_DIM * K_DIM;
  float* gates = (float*)(wb + (size_t)NSEG * N_DIM * K_DIM);

  convert_kernel<<<2048, 256, 0, stream>>>(x, xb, B_DIM * K_DIM / 8);
  convert_kernel<<<2048, 256, 0, stream>>>(W_seg, wb, NSEG * N_DIM * K_DIM / 8);
  gates_kernel<<<B_DIM, 256, 0, stream>>>(x, W_gate, b_gate, gates);

  dim3 grid(N_DIM / BN, B_DIM / BM);   // (64, 64)
  seg_gemm_kernel<<<grid, 256, 0, stream>>>(xb, wb, b_seg, thr, gates, out);
}

// Round 2
// 316.128 us; speedup vs baseline: 1.2808x; 1.2808x over previous
//
#include <hip/hip_runtime.h>
#include <hip/hip_bf16.h>
#include <stdint.h>

#define B_DIM 8192
#define K_DIM 2048
#define N_DIM 2048
#define NSEG 4
#define NT (K_DIM / 64)   // 32 K-tiles of BK=64

typedef short bf16x8 __attribute__((ext_vector_type(8)));   // 8 bf16 (4 VGPRs)
typedef float f32x4 __attribute__((ext_vector_type(4)));
typedef unsigned short ushort8v __attribute__((ext_vector_type(8)));

typedef const __attribute__((address_space(1))) void* gas_ptr;
typedef __attribute__((address_space(3))) void* lds_ptr;

__device__ __forceinline__ unsigned short f2bf(float f) {
  uint32_t u = __float_as_uint(f);
  u += 0x7FFFu + ((u >> 16) & 1u);   // round-to-nearest-even
  return (unsigned short)(u >> 16);
}

// ---------------- W: f32 -> bf16 conversion, 8 elems/thread ----------------
__global__ __launch_bounds__(256)
void convert_kernel(const float* __restrict__ in, unsigned short* __restrict__ out, int n8) {
  int i = blockIdx.x * blockDim.x + threadIdx.x;
  const int stride = gridDim.x * blockDim.x;
  for (; i < n8; i += stride) {
    const float4* p = (const float4*)(in + (size_t)i * 8);
    float4 v0 = p[0];
    float4 v1 = p[1];
    ushort8v r;
    r[0] = f2bf(v0.x); r[1] = f2bf(v0.y); r[2] = f2bf(v0.z); r[3] = f2bf(v0.w);
    r[4] = f2bf(v1.x); r[5] = f2bf(v1.y); r[6] = f2bf(v1.z); r[7] = f2bf(v1.w);
    *(ushort8v*)(out + (size_t)i * 8) = r;
  }
}

// ------ fused: x f32 -> bf16 convert + gates = sigmoid(x @ Wg^T + bg) ------
// one block per batch row; 256 threads x 8 elems = 2048.
__global__ __launch_bounds__(256)
void xconv_gates_kernel(const float* __restrict__ x, const float* __restrict__ Wg,
                        const float* __restrict__ bg,
                        unsigned short* __restrict__ xb, float* __restrict__ gates) {
  const int b = blockIdx.x;
  const int tid = threadIdx.x;
  const size_t base = (size_t)b * K_DIM + tid * 8;
  const float4 v0 = *(const float4*)(x + base);
  const float4 v1 = *(const float4*)(x + base + 4);
  ushort8v r;
  r[0] = f2bf(v0.x); r[1] = f2bf(v0.y); r[2] = f2bf(v0.z); r[3] = f2bf(v0.w);
  r[4] = f2bf(v1.x); r[5] = f2bf(v1.y); r[6] = f2bf(v1.z); r[7] = f2bf(v1.w);
  *(ushort8v*)(xb + base) = r;

  float a[4];
#pragma unroll
  for (int s = 0; s < 4; ++s) {
    const float4 w0 = *(const float4*)(Wg + (size_t)s * K_DIM + tid * 8);
    const float4 w1 = *(const float4*)(Wg + (size_t)s * K_DIM + tid * 8 + 4);
    a[s] = v0.x * w0.x + v0.y * w0.y + v0.z * w0.z + v0.w * w0.w
         + v1.x * w1.x + v1.y * w1.y + v1.z * w1.z + v1.w * w1.w;
  }
#pragma unroll
  for (int off = 1; off < 64; off <<= 1) {
#pragma unroll
    for (int s = 0; s < 4; ++s) a[s] += __shfl_xor(a[s], off);
  }
  __shared__ float red[4][4];
  const int wv = tid >> 6;
  if ((tid & 63) == 0) {
#pragma unroll
    for (int s = 0; s < 4; ++s) red[wv][s] = a[s];
  }
  __syncthreads();
  if (tid < 4) {
    float v = red[0][tid] + red[1][tid] + red[2][tid] + red[3][tid] + bg[tid];
    gates[(size_t)b * 4 + tid] = 1.f / (1.f + __expf(-v));
  }
}

// ---------------- fused 4-segment GEMM, 8-phase 256-eff^2 schedule ----------
// Block: 256 batch rows x (4 segs x 64 d-cols) = 256x256 effective C-tile.
// 512 threads = 8 waves as 2(M) x 4(N_d): wave (wm,wn) owns rows wm*128..+128,
// d-cols wn*16..+16 for ALL 4 segments (epilogue needs all segs in-lane).
// LDS 128 KiB dynamic: A[2 dbuf][2 half][128x64 bf16] + B same, subtiled
// st_16x32 layout with XOR-bit5-by-bit9 swizzle (both-sides: pre-swizzled
// global_load_lds source + swizzled ds_read addresses).
//
// Per K-tile (BK=64): 4 phases; phase p computes m-frags {2p,2p+1} x 4 segs
// x kk{0,1} = 16 MFMA. Stages: p0 A(t+1).h0, p1 A(t+1).h1 (other dbuf, safe),
// p2 B(t+2).h0, p3 B(t+2).h1 (same-parity B region is dead after p0's B->reg
// reads + p0 closing barrier). End-of-tile: s_waitcnt vmcnt(4) THEN s_barrier
// => every wave's own loads for tile t+1 are complete before any wave reads,
// while the newest 4 loads (B(t+2)) stay in flight across the barrier.
__global__ __launch_bounds__(512, 2)
void seg_gemm_kernel(const unsigned short* __restrict__ Xb,
                     const unsigned short* __restrict__ Wb,
                     const float* __restrict__ b_seg,
                     const float* __restrict__ thr,
                     const float* __restrict__ gates,
                     float* __restrict__ out) {
  extern __shared__ __align__(128) char smem[];   // 131072 bytes

  const int tid = threadIdx.x;
  const int lane = tid & 63;
  const int wid = tid >> 6;
  const int wm = wid >> 2;        // 0..1
  const int wn = wid & 3;         // 0..3

  // bijective XCD swizzle: 1024 blocks, 8 XCDs, 128 per XCD (contiguous bm)
  const int id = blockIdx.x;
  const int swz = (id & 7) * 128 + (id >> 3);
  const int m0 = (swz >> 5) * 256;
  const int n0 = (swz & 31) * 64;

  // ---- staging per-thread constants (inverse of subtiled+swizzled layout) --
  // LDS linear dest L = tid*16 (+ j*8192).  L' = L ^ ((bit9 of L)<<5):
  const int row_st = ((tid >> 7) << 4) + ((tid >> 2) & 15);          // + j*64
  const int kb_st  = (((tid >> 6) & 1) << 6) + ((((tid & 3) << 4)) ^ (((tid >> 5) & 1) << 5));
  const int ke_st  = kb_st >> 1;                                     // k element 0..63
  const int ldsd   = tid * 16;                                       // dest byte in halfbuf

  // ---- read-side per-thread constants ----
  const int l15 = lane & 15;
  const int kg  = lane >> 4;       // 0..3
  // addr within halfbuf for (row = f*16+l15, kbyte = kk*64 + kg*16), subtiled:
  //   f*2048 + kk*1024 + l15*64 + kg*16, then XOR bit5 by bit9 (= l15>>3):
  const int aRd = l15 * 64 + ((kg * 16) ^ ((l15 & 8) << 2));
  const int wnB = wn * 2048;

  f32x4 acc[NSEG][8];
#pragma unroll
  for (int s = 0; s < NSEG; ++s)
#pragma unroll
    for (int f = 0; f < 8; ++f) acc[s][f] = (f32x4){0.f, 0.f, 0.f, 0.f};

#define STAGE_A(t_, h_) do { int buf_ = (t_) & 1;                                   \
    const unsigned short* s0_ = Xb + (size_t)(m0 + (h_) * 128 + row_st) * K_DIM + (t_) * 64 + ke_st; \
    __builtin_amdgcn_global_load_lds((gas_ptr)s0_, (lds_ptr)(smem + buf_ * 32768 + (h_) * 16384 + ldsd), 16, 0, 0); \
    const unsigned short* s1_ = Xb + (size_t)(m0 + (h_) * 128 + row_st + 64) * K_DIM + (t_) * 64 + ke_st; \
    __builtin_amdgcn_global_load_lds((gas_ptr)s1_, (lds_ptr)(smem + buf_ * 32768 + (h_) * 16384 + ldsd + 8192), 16, 0, 0); \
  } while (0)

#define STAGE_B(t_, h_) do { int buf_ = (t_) & 1;                                   \
    int e0_ = (h_) * 128 + row_st;                                                  \
    const unsigned short* s0_ = Wb + (size_t)(e0_ >> 6) * (N_DIM * K_DIM) + (size_t)(n0 + (e0_ & 63)) * K_DIM + (t_) * 64 + ke_st; \
    __builtin_amdgcn_global_load_lds((gas_ptr)s0_, (lds_ptr)(smem + 65536 + buf_ * 32768 + (h_) * 16384 + ldsd), 16, 0, 0); \
    int e1_ = e0_ + 64;                                                             \
    const unsigned short* s1_ = Wb + (size_t)(e1_ >> 6) * (N_DIM * K_DIM) + (size_t)(n0 + (e1_ & 63)) * K_DIM + (t_) * 64 + ke_st; \
    __builtin_amdgcn_global_load_lds((gas_ptr)s1_, (lds_ptr)(smem + 65536 + buf_ * 32768 + (h_) * 16384 + ldsd + 8192), 16, 0, 0); \
  } while (0)

#define MFMA16x16 __builtin_amdgcn_mfma_f32_16x16x32_bf16

#define PHASE_TAIL(f0_, STAGE_STMT, TAIL_STMT) do {                                 \
    bf16x8 a00 = *(const bf16x8*)(Ab + (f0_) * 2048 + aRd);                         \
    bf16x8 a01 = *(const bf16x8*)(Ab + (f0_) * 2048 + 1024 + aRd);                  \
    bf16x8 a10 = *(const bf16x8*)(Ab + ((f0_) + 1) * 2048 + aRd);                   \
    bf16x8 a11 = *(const bf16x8*)(Ab + ((f0_) + 1) * 2048 + 1024 + aRd);            \
    STAGE_STMT;                                                                     \
    asm volatile("s_barrier" ::: "memory");                                         \
    asm volatile("s_waitcnt lgkmcnt(0)" ::: "memory");                              \
    __builtin_amdgcn_s_setprio(1);                                                  \
    _Pragma("unroll")                                                               \
    for (int s = 0; s < NSEG; ++s) {                                                \
      acc[s][(f0_)]     = MFMA16x16(a00, bfr[s][0], acc[s][(f0_)], 0, 0, 0);        \
      acc[s][(f0_) + 1] = MFMA16x16(a10, bfr[s][0], acc[s][(f0_) + 1], 0, 0, 0);    \
    }                                                                               \
    _Pragma("unroll")                                                               \
    for (int s = 0; s < NSEG; ++s) {                                                \
      acc[s][(f0_)]     = MFMA16x16(a01, bfr[s][1], acc[s][(f0_)], 0, 0, 0);        \
      acc[s][(f0_) + 1] = MFMA16x16(a11, bfr[s][1], acc[s][(f0_) + 1], 0, 0, 0);    \
    }                                                                               \
    __builtin_amdgcn_s_setprio(0);                                                  \
    TAIL_STMT;                                                                      \
    asm volatile("s_barrier" ::: "memory");                                         \
  } while (0)

  // ---- prologue: A(0).h0/h1, B(0).h0/h1, B(1).h0/h1; keep B(1) in flight ----
  STAGE_A(0, 0); STAGE_A(0, 1);
  STAGE_B(0, 0); STAGE_B(0, 1);
  STAGE_B(1, 0); STAGE_B(1, 1);
  asm volatile("s_waitcnt vmcnt(4)" ::: "memory");
  asm volatile("s_barrier" ::: "memory");

  for (int t = 0; t < NT; ++t) {
    const int cb = t & 1;
    const char* Ab = smem + cb * 32768 + wm * 16384;
    const char* Bb = smem + 65536 + cb * 32768;
    bf16x8 bfr[NSEG][2];

    // ---- phase 0: B frags -> regs, m-frags 0,1; stage A(t+1).h0 ----
    {
#pragma unroll
      for (int s = 0; s < NSEG; ++s) {
        const char* bp = Bb + (s >> 1) * 16384 + (s & 1) * 8192 + wnB + aRd;
        bfr[s][0] = *(const bf16x8*)(bp);
        bfr[s][1] = *(const bf16x8*)(bp + 1024);
      }
      PHASE_TAIL(0, { if (t + 1 < NT) STAGE_A(t + 1, 0); }, {});
    }
    // ---- phase 1: m-frags 2,3; stage A(t+1).h1 ----
    PHASE_TAIL(2, { if (t + 1 < NT) STAGE_A(t + 1, 1); }, {});
    // ---- phase 2: m-frags 4,5; stage B(t+2).h0 ----
    PHASE_TAIL(4, { if (t + 2 < NT) STAGE_B(t + 2, 0); }, {});
    // ---- phase 3: m-frags 6,7; stage B(t+2).h1; counted vmcnt then barrier --
    PHASE_TAIL(6, { if (t + 2 < NT) STAGE_B(t + 2, 1); },
               {
                 if (t < NT - 2) { asm volatile("s_waitcnt vmcnt(4)" ::: "memory"); }
                 else if (t == NT - 2) { asm volatile("s_waitcnt vmcnt(0)" ::: "memory"); }
               });
  }

  // ---------------- epilogue ----------------
  // C/D layout: col = lane&15 (d), row = (lane>>4)*4 + reg (batch) [verified R1]
  const int d = n0 + wn * 16 + l15;
  float bsv[NSEG], thv[NSEG];
#pragma unroll
  for (int s = 0; s < NSEG; ++s) {
    bsv[s] = b_seg[s * N_DIM + d];
    thv[s] = thr[s * N_DIM + d];
  }
#pragma unroll
  for (int f = 0; f < 8; ++f) {
#pragma unroll
    for (int r = 0; r < 4; ++r) {
      const int brow = m0 + wm * 128 + f * 16 + kg * 4 + r;
      const float4 g = *(const float4*)(gates + (size_t)brow * 4);
      const float gv[NSEG] = {g.x, g.y, g.z, g.w};
      float sum = 0.f, prod = 1.f;
#pragma unroll
      for (int s = 0; s < NSEG; ++s) {
        const float seg = acc[s][f][r] + bsv[s];
        const float pl = 1.f / (1.f + __expf(-5.f * (seg - thv[s])));
        const float st = seg * pl * gv[s];
        sum += st;
        prod *= st;
      }
      const float gm = sqrtf(sqrtf(fabsf(prod)));   // |prod|^(1/4)
      out[(size_t)brow * N_DIM + d] = sum + 0.1f * (prod < 0.f ? -gm : gm);
    }
  }
#undef STAGE_A
#undef STAGE_B
#undef PHASE_TAIL
#undef MFMA16x16
}

extern "C" void kernel_launch(void* const* d_in, const int* in_sizes, int n_in,
                              void* d_out, int out_size, void* d_ws, size_t ws_size,
                              hipStream_t stream) {
  const float* x      = (const float*)d_in[0];
  const float* W_seg  = (const float*)d_in[1];
  const float* b_seg  = (const float*)d_in[2];
  const float* thr    = (const float*)d_in[3];
  const float* W_gate = (const float*)d_in[4];
  const float* b_gate = (const float*)d_in[5];
  float* out = (float*)d_out;

  // workspace layout: x_bf16 (32MB) | W_bf16 (32MB) | gates (128KB)
  unsigned short* xb = (unsigned short*)d_ws;
  unsigned short* wb = xb + (size_t)B_DIM * K_DIM;
  float* gates = (float*)(wb + (size_t)NSEG * N_DIM * K_DIM);

  xconv_gates_kernel<<<B_DIM, 256, 0, stream>>>(x, W_gate, b_gate, xb, gates);
  convert_kernel<<<2048, 256, 0, stream>>>(W_seg, wb, NSEG * N_DIM * K_DIM / 8);

  hipFuncSetAttribute((const void*)seg_gemm_kernel,
                      hipFuncAttributeMaxDynamicSharedMemorySize, 131072);
  seg_gemm_kernel<<<1024, 512, 131072, stream>>>(xb, wb, b_seg, thr, gates, out);
}